// Round 2
// baseline (332.890 us; speedup 1.0000x reference)
//
#include <hip/hip_runtime.h>
#include <hip/hip_bf16.h>

#define NB 2
#define NL 2048
#define ND 2048
#define NH 16
#define NDK 128
#define SCALE 0.08838834764831845f

#define AS1 __attribute__((address_space(1)))
#define AS3 __attribute__((address_space(3)))

typedef __attribute__((ext_vector_type(8))) __bf16 bf16x8;
typedef __attribute__((ext_vector_type(4))) float f32x4;

__device__ __forceinline__ unsigned short f2bf(float f) {
    union { float f; unsigned u; } v; v.f = f;
    return (unsigned short)((v.u + 0x7fffu + ((v.u >> 16) & 1u)) >> 16);
}
__device__ __forceinline__ float bf2f(unsigned short h) {
    union { unsigned u; float f; } v; v.u = ((unsigned)h) << 16;
    return v.f;
}

// ============ fp32 -> bf16 flat convert (x) =============================================
__global__ __launch_bounds__(256)
void convert_bf16_kernel(const float* __restrict__ in, unsigned short* __restrict__ outp)
{
    int i = blockIdx.x * 256 + threadIdx.x;
    const float4 a = ((const float4*)in)[2 * i];
    const float4 b = ((const float4*)in)[2 * i + 1];
    unsigned short t[8] = { f2bf(a.x), f2bf(a.y), f2bf(a.z), f2bf(a.w),
                            f2bf(b.x), f2bf(b.y), f2bf(b.z), f2bf(b.w) };
    ((uint4*)outp)[i] = *(uint4*)t;
}

// ============ fp32 (R x C) -> bf16 transposed (C x R), 64x64 LDS tiles ==================
__global__ __launch_bounds__(256)
void transpose_convert_kernel(const float* __restrict__ in, unsigned short* __restrict__ outp,
                              int R, int C)
{
    __shared__ float T[64][65];
    const int tr0 = blockIdx.y * 64;
    const int tc0 = blockIdx.x * 64;
    const int t = threadIdx.x;
    const int r = t >> 2;
    const int q = t & 3;
    const float* src = in + (size_t)(tr0 + r) * C + tc0 + q * 16;
    #pragma unroll
    for (int i = 0; i < 4; i++) {
        float4 f = *(const float4*)(src + 4 * i);
        T[r][q * 16 + 4 * i + 0] = f.x;
        T[r][q * 16 + 4 * i + 1] = f.y;
        T[r][q * 16 + 4 * i + 2] = f.z;
        T[r][q * 16 + 4 * i + 3] = f.w;
    }
    __syncthreads();
    unsigned short tmp[16];
    #pragma unroll
    for (int i = 0; i < 16; i++) tmp[i] = f2bf(T[q * 16 + i][r]);
    unsigned short* dst = outp + (size_t)(tc0 + r) * R + tr0 + q * 16;
    *(uint4*)dst       = *(uint4*)&tmp[0];
    *(uint4*)(dst + 8) = *(uint4*)&tmp[8];
}

// ============ per-head V transpose: v fp32 (BH, L, DK) -> Vt bf16 (BH, DK, L) ===========
__global__ __launch_bounds__(256)
void transpose_v_kernel(const float* __restrict__ v, unsigned short* __restrict__ vt)
{
    __shared__ float T[64][65];
    const int bh = blockIdx.z;
    const int l0 = blockIdx.y * 64;
    const int d0 = blockIdx.x * 64;
    const int t = threadIdx.x;
    const int r = t >> 2;
    const int q = t & 3;
    const float* src = v + (size_t)bh * NL * NDK + (size_t)(l0 + r) * NDK + d0 + q * 16;
    #pragma unroll
    for (int i = 0; i < 4; i++) {
        float4 f = *(const float4*)(src + 4 * i);
        T[r][q * 16 + 4 * i + 0] = f.x;
        T[r][q * 16 + 4 * i + 1] = f.y;
        T[r][q * 16 + 4 * i + 2] = f.z;
        T[r][q * 16 + 4 * i + 3] = f.w;
    }
    __syncthreads();
    unsigned short tmp[16];
    #pragma unroll
    for (int i = 0; i < 16; i++) tmp[i] = f2bf(T[q * 16 + i][r]);
    unsigned short* dst = vt + (size_t)bh * NDK * NL + (size_t)(d0 + r) * NL + l0 + q * 16;
    *(uint4*)dst       = *(uint4*)&tmp[0];
    *(uint4*)(dst + 8) = *(uint4*)&tmp[8];
}

// ============ 4-phase deep-pipelined bf16 GEMM (T2+T3+T4+T5): C = A @ Bt^T ==============
// BM=128, BN=256, BK=64, 512 thr (8 waves 2x4), 2 LDS buffers (96 KiB), counted vmcnt(2).
// Per iteration = 2 K-steps = 4 phases of {ds_read subtile | stage | bar | lgkm0 | 16 MFMA | bar}.
// Staging schedule (derived from consumption order; buf parity = K-step parity):
//   ph1: B(2i+1) both halves   (buf1.B last read prev ph4)
//   ph2: A(2i+2)               (buf0.A consumed after ph1)     + vmcnt(2) [step 2i+1 landed]
//   ph3: B(2i+2) both halves   (buf0.B consumed after ph2)
//   ph4: A(2i+3)               (buf1.A consumed after ph3)     + vmcnt(2) [step 2i+2 landed]
// Final iteration peeled: stages only B(2i+1), drains vmcnt(0) at ph2. No OOB reads.
// LDS swizzle: 8-chunk rows, store chunk c at c^(row&7) via pre-swizzled GLOBAL source
// (global_load_lds dest stays linear -- rule #21), read with same XOR.
// NOTE round-1 bug: NTB must equal N/256 of the actual call site (o-proj: 8, NOT 16).
template<int EPI>
__global__ __launch_bounds__(512, 2)
void gemm256(const unsigned short* __restrict__ A, const unsigned short* __restrict__ Bt,
             float* __restrict__ y_dst,
             unsigned short* __restrict__ q_raw,
             float* __restrict__ k_dst, float* __restrict__ v_dst,
             int K, int NTB)
{
    __shared__ __align__(16) unsigned short As[2][128][64];   // 32 KiB
    __shared__ __align__(16) unsigned short Bs[2][256][64];   // 64 KiB

    const int tid = threadIdx.x;
    const int lane = tid & 63;
    const int w = tid >> 6;                // 0..7
    const int wr = w >> 2, wc = w & 3;     // 2 x 4 wave grid
    const int l16 = lane & 15, g = lane >> 4;

    // XCD-chunked block swizzle (NTB % 8 == 0 not required; NTB*MT % 8 == 0 holds here)
    const int cpn = NTB >> 3 ? NTB >> 3 : 1;
    const int bid = blockIdx.x;
    int bx, by;
    if (NTB >= 8) {
        const int xcd = bid & 7, local = bid >> 3;
        bx = xcd * (NTB >> 3) + local % (NTB >> 3);
        by = local / (NTB >> 3);
    } else {
        bx = bid % NTB;
        by = bid / NTB;
    }
    (void)cpn;
    const int m0 = by * 128, n0 = bx * 256;

    char* const asb = (char*)&As[0][0][0];
    char* const bsb = (char*)&Bs[0][0][0];

    // ---- staging addresses (pre-swizzled global source, linear LDS dest) ----
    const int srow = w * 16 + (lane >> 3);                    // 0..127
    const int swz  = ((lane & 7) ^ (lane >> 3)) << 3;         // element offset
    const unsigned short* const gA0 = A  + (size_t)(m0 + srow) * K + swz;
    const unsigned short* const gB0 = Bt + (size_t)(n0 + srow) * K + swz;
    const int sdst = srow * 128 + ((lane & 7) << 4);          // per-lane = wavebase + lane*16

    auto STA = [&](int buf, int k0) {
        const unsigned short* s = gA0 + k0;
        char* d = asb + buf * 16384 + sdst;
        __builtin_amdgcn_global_load_lds((const AS1 void*)(s),         (AS3 void*)(d),        16, 0, 0);
        __builtin_amdgcn_global_load_lds((const AS1 void*)(s + 8 * K), (AS3 void*)(d + 1024), 16, 0, 0);
    };
    auto STB = [&](int buf, int R0, int k0) {
        const unsigned short* s = gB0 + (size_t)R0 * K + k0;
        char* d = bsb + buf * 32768 + R0 * 128 + sdst;
        __builtin_amdgcn_global_load_lds((const AS1 void*)(s),         (AS3 void*)(d),        16, 0, 0);
        __builtin_amdgcn_global_load_lds((const AS1 void*)(s + 8 * K), (AS3 void*)(d + 1024), 16, 0, 0);
    };

    // ---- fragment read addresses (XOR-swizzled chunks) ----
    const int xr = l16 & 7;
    const int aRow = (wr * 64 + l16) * 128;
    const int bRow = (wc * 64 + l16) * 128;
    const int cp0 = ((0 + g) ^ xr) << 4;   // ks=0 chunk position (bytes)
    const int cp1 = ((4 + g) ^ xr) << 4;   // ks=1

    f32x4 acc[4][4] = {};
    bf16x8 af[4][2], bfr[4][2];

    auto LDA4 = [&](int buf) {
        const char* p = asb + buf * 16384 + aRow;
        #pragma unroll
        for (int f = 0; f < 4; f++) {
            af[f][0] = *(const bf16x8*)(p + f * 2048 + cp0);
            af[f][1] = *(const bf16x8*)(p + f * 2048 + cp1);
        }
    };
    auto LDB2 = [&](int buf, int f0) {
        const char* p = bsb + buf * 32768 + bRow + f0 * 2048;
        #pragma unroll
        for (int f = 0; f < 2; f++) {
            bfr[f0 + f][0] = *(const bf16x8*)(p + f * 2048 + cp0);
            bfr[f0 + f][1] = *(const bf16x8*)(p + f * 2048 + cp1);
        }
    };
    auto MM16 = [&](int nf0) {
        __builtin_amdgcn_s_setprio(1);
        #pragma unroll
        for (int mf = 0; mf < 4; mf++)
            #pragma unroll
            for (int nf = 0; nf < 2; nf++) {
                f32x4 c = acc[mf][nf0 + nf];
                c = __builtin_amdgcn_mfma_f32_16x16x32_bf16(af[mf][0], bfr[nf0 + nf][0], c, 0, 0, 0);
                c = __builtin_amdgcn_mfma_f32_16x16x32_bf16(af[mf][1], bfr[nf0 + nf][1], c, 0, 0, 0);
                acc[mf][nf0 + nf] = c;
            }
        __builtin_amdgcn_s_setprio(0);
    };
    auto PH_TOP = [&]() {
        __builtin_amdgcn_s_barrier();
        asm volatile("s_waitcnt lgkmcnt(0)" ::: "memory");
        __builtin_amdgcn_sched_barrier(0);
    };
    auto PH_END = [&]() {
        __builtin_amdgcn_s_barrier();
        __builtin_amdgcn_sched_barrier(0);
    };

    auto ITER = [&](bool full, int kb1, int kn) {
        // ---- ph1: compute step 2i (buf0) quadrant N0-1 ----
        LDA4(0); LDB2(0, 0);
        STB(1, 0, kb1); STB(1, 128, kb1);
        PH_TOP(); MM16(0); PH_END();
        // ---- ph2: quadrant N2-3 ----
        LDB2(0, 2);
        if (full) STA(0, kn);
        PH_TOP(); MM16(2);
        if (full) asm volatile("s_waitcnt vmcnt(2)" ::: "memory");
        else      asm volatile("s_waitcnt vmcnt(0)" ::: "memory");
        __builtin_amdgcn_sched_barrier(0);
        PH_END();
        // ---- ph3: compute step 2i+1 (buf1) quadrant N0-1 ----
        LDA4(1); LDB2(1, 0);
        if (full) { STB(0, 0, kn); STB(0, 128, kn); }
        PH_TOP(); MM16(0); PH_END();
        // ---- ph4: quadrant N2-3 ----
        LDB2(1, 2);
        if (full) STA(1, kn + 64);
        PH_TOP(); MM16(2);
        if (full) {
            asm volatile("s_waitcnt vmcnt(2)" ::: "memory");
            __builtin_amdgcn_sched_barrier(0);
        }
        PH_END();
    };

    // ---- prologue: stage step 0 (buf0) + A(1); land step 0, keep A(1) in flight ----
    STA(0, 0);
    STB(0, 0, 0); STB(0, 128, 0);
    STA(1, 64);
    asm volatile("s_waitcnt vmcnt(2)" ::: "memory");
    __builtin_amdgcn_s_barrier();
    __builtin_amdgcn_sched_barrier(0);

    const int NI = K >> 7;                 // iterations of 2 K-steps (BK=64)
    for (int i = 0; i < NI - 1; i++)
        ITER(true, i * 128 + 64, i * 128 + 128);
    ITER(false, (NI - 1) * 128 + 64, 0);   // peeled: no out-of-range staging

    // ---- epilogue ----
    if constexpr (EPI == 0) {
        #pragma unroll
        for (int mf = 0; mf < 4; mf++) {
            const int mrow = m0 + wr * 64 + mf * 16 + g * 4;
            const int b = mrow >> 11, l = mrow & 2047;
            #pragma unroll
            for (int nf = 0; nf < 4; nf++) {
                const int ncol = n0 + wc * 64 + nf * 16 + l16;
                const int sec = ncol >> 11;           // 0=q, 1=k, 2=v (block-uniform)
                const int dd = ncol & 2047;
                const int h = dd >> 7, dk = dd & 127;
                const size_t rb = ((size_t)(b * NH + h) * NL + l) * NDK + dk;
                #pragma unroll
                for (int i2 = 0; i2 < 4; i2++) {
                    const float val = acc[mf][nf][i2];
                    const size_t off = rb + (size_t)i2 * NDK;
                    if (sec == 0)      q_raw[off] = f2bf(val);
                    else if (sec == 1) k_dst[off] = val;
                    else               v_dst[off] = val;
                }
            }
        }
    } else {
        #pragma unroll
        for (int mf = 0; mf < 4; mf++) {
            const int mrow = m0 + wr * 64 + mf * 16 + g * 4;
            #pragma unroll
            for (int nf = 0; nf < 4; nf++) {
                const int ncol = n0 + wc * 64 + nf * 16 + l16;
                #pragma unroll
                for (int i2 = 0; i2 < 4; i2++)
                    y_dst[(size_t)(mrow + i2) * ND + ncol] = acc[mf][nf][i2];
            }
        }
    }
}

// ============ RoPE on k only: fp32 in-place (final) + bf16 copy =========================
__global__ __launch_bounds__(256)
void rope_k_kernel(float* __restrict__ kp, unsigned short* __restrict__ k_bf,
                   const float* __restrict__ ct, const float* __restrict__ st)
{
    int idx = blockIdx.x * 256 + threadIdx.x;
    int d = idx & 63;
    int rr = idx >> 6;
    size_t ro = (size_t)rr * NDK;
    int l = rr & (NL - 1);
    float c = ct[l * 64 + d], s = st[l * 64 + d];
    float t1 = kp[ro + d], t2 = kp[ro + d + 64];
    float o1 = t1 * c - t2 * s, o2 = t1 * s + t2 * c;
    kp[ro + d] = o1; kp[ro + d + 64] = o2;
    k_bf[ro + d]      = f2bf(o1);
    k_bf[ro + d + 64] = f2bf(o2);
}

// ============ MFMA flash attention (round-10 structure + named-reg T14 + setprio) =======
__global__ __launch_bounds__(256)
void attn_kernel(const unsigned short* __restrict__ q,
                 const unsigned short* __restrict__ k,
                 const unsigned short* __restrict__ vt,
                 unsigned short* __restrict__ attn_out,
                 const float* __restrict__ ct, const float* __restrict__ st)
{
    __shared__ __align__(16) unsigned short Ks[64][128];
    __shared__ __align__(16) unsigned short Vts[128][64];
    __shared__ __align__(16) unsigned short Ps[4][16][64];

    char* const ksb = (char*)&Ks[0][0];
    char* const vsb = (char*)&Vts[0][0];
    char* const psb = (char*)&Ps[0][0][0];

    const int tid = threadIdx.x, lane = tid & 63, w = tid >> 6;
    const int l16 = lane & 15, g = lane >> 4;
    const int bh = blockIdx.x;
    const int b = bh >> 4, h = bh & 15;
    const size_t base = (size_t)bh * NL * NDK;

    const int krow = tid >> 2;
    const int kq = tid & 3;
    const int kwb = krow * 256 + kq * 64;
    const int kwx = (krow & 7) << 4;
    const int vrow = tid >> 1;
    const int vh = tid & 1;
    const int vwb = vrow * 128 + vh * 64;
    const int vwx = (vrow & 7) << 4;

    const int rdx = (l16 & 7) << 4;

    const unsigned short* const kbase = k + base + (size_t)krow * NDK + kq * 32;
    const unsigned short* const vbase = vt + base + (size_t)vrow * NL + vh * 32;

    for (int half = 0; half < 2; half++) {
        const int jq = half ? (int)blockIdx.y : 31 - (int)blockIdx.y;
        const int qb = jq * 64;

        // ---- Q load with fused RoPE ----
        bf16x8 aq[4];
        {
            const int l = qb + w * 16 + l16;
            const unsigned short* src = q + base + (size_t)l * NDK + g * 8;
            union { bf16x8 v; unsigned short s[8]; } raw[4], outv[4];
            #pragma unroll
            for (int ks2 = 0; ks2 < 4; ks2++) raw[ks2].v = *(const bf16x8*)(src + ks2 * 32);
            const float* cb = ct + (size_t)l * 64 + g * 8;
            const float* sb = st + (size_t)l * 64 + g * 8;
            float cv[2][8], sv2[2][8];
            #pragma unroll
            for (int hh = 0; hh < 2; hh++) {
                float4 c0 = *(const float4*)(cb + 32 * hh);
                float4 c1 = *(const float4*)(cb + 32 * hh + 4);
                float4 s0 = *(const float4*)(sb + 32 * hh);
                float4 s1 = *(const float4*)(sb + 32 * hh + 4);
                cv[hh][0]=c0.x; cv[hh][1]=c0.y; cv[hh][2]=c0.z; cv[hh][3]=c0.w;
                cv[hh][4]=c1.x; cv[hh][5]=c1.y; cv[hh][6]=c1.z; cv[hh][7]=c1.w;
                sv2[hh][0]=s0.x; sv2[hh][1]=s0.y; sv2[hh][2]=s0.z; sv2[hh][3]=s0.w;
                sv2[hh][4]=s1.x; sv2[hh][5]=s1.y; sv2[hh][6]=s1.z; sv2[hh][7]=s1.w;
            }
            #pragma unroll
            for (int hh = 0; hh < 2; hh++)
                #pragma unroll
                for (int j = 0; j < 8; j++) {
                    float t1 = bf2f(raw[hh].s[j]), t2 = bf2f(raw[hh + 2].s[j]);
                    float c = cv[hh][j], s = sv2[hh][j];
                    outv[hh].s[j]     = f2bf(t1 * c - t2 * s);
                    outv[hh + 2].s[j] = f2bf(t1 * s + t2 * c);
                }
            #pragma unroll
            for (int ks2 = 0; ks2 < 4; ks2++) aq[ks2] = outv[ks2].v;
        }

        f32x4 o[8] = {};
        float m_r[4], lv[4];
        #pragma unroll
        for (int i = 0; i < 4; i++) { m_r[i] = -1e30f; lv[i] = 0.f; }

        // ---- T14 prologue: tile 0 into named registers ----
        uint4 pk0, pk1, pk2, pk3, pv0, pv1, pv2, pv3;
        {
            const unsigned short* ks = kbase;
            pk0 = *(const uint4*)(ks);
            pk1 = *(const uint4*)(ks + 8);
            pk2 = *(const uint4*)(ks + 16);
            pk3 = *(const uint4*)(ks + 24);
            const unsigned short* vs = vbase;
            pv0 = *(const uint4*)(vs);
            pv1 = *(const uint4*)(vs + 8);
            pv2 = *(const uint4*)(vs + 16);
            pv3 = *(const uint4*)(vs + 24);
        }

        for (int kv0 = 0; kv0 <= qb; kv0 += 64) {
            __syncthreads();
            *(uint4*)(ksb + ((kwb     ) ^ kwx)) = pk0;
            *(uint4*)(ksb + ((kwb + 16) ^ kwx)) = pk1;
            *(uint4*)(ksb + ((kwb + 32) ^ kwx)) = pk2;
            *(uint4*)(ksb + ((kwb + 48) ^ kwx)) = pk3;
            *(uint4*)(vsb + ((vwb     ) ^ vwx)) = pv0;
            *(uint4*)(vsb + ((vwb + 16) ^ vwx)) = pv1;
            *(uint4*)(vsb + ((vwb + 32) ^ vwx)) = pv2;
            *(uint4*)(vsb + ((vwb + 48) ^ vwx)) = pv3;
            __syncthreads();

            if (kv0 + 64 <= qb) {
                const unsigned short* ks = kbase + (size_t)(kv0 + 64) * NDK;
                pk0 = *(const uint4*)(ks);
                pk1 = *(const uint4*)(ks + 8);
                pk2 = *(const uint4*)(ks + 16);
                pk3 = *(const uint4*)(ks + 24);
                const unsigned short* vs = vbase + kv0 + 64;
                pv0 = *(const uint4*)(vs);
                pv1 = *(const uint4*)(vs + 8);
                pv2 = *(const uint4*)(vs + 16);
                pv3 = *(const uint4*)(vs + 24);
                __builtin_amdgcn_sched_barrier(0);
            }

            // ---- QK^T: 16 MFMAs ----
            f32x4 sv[4];
            __builtin_amdgcn_s_setprio(1);
            #pragma unroll
            for (int cf = 0; cf < 4; cf++) {
                const int krb = (cf * 16 + l16) * 256 + g * 16;
                f32x4 a = {};
                #pragma unroll
                for (int ks2 = 0; ks2 < 4; ks2++) {
                    bf16x8 kf = *(const bf16x8*)(ksb + ((krb + 64 * ks2) ^ rdx));
                    a = __builtin_amdgcn_mfma_f32_16x16x32_bf16(aq[ks2], kf, a, 0, 0, 0);
                }
                sv[cf] = a;
            }
            __builtin_amdgcn_s_setprio(0);

            // ---- online softmax (deferred l-sum) ----
            const int kvl = kv0 + l16;
            const int rowb = qb + w * 16 + g * 4;
            #pragma unroll
            for (int i = 0; i < 4; i++) {
                int row = rowb + i;
                float s0 = sv[0][i] * SCALE;
                float s1 = sv[1][i] * SCALE;
                float s2 = sv[2][i] * SCALE;
                float s3 = sv[3][i] * SCALE;
                if (kvl      > row) s0 = -1e30f;
                if (kvl + 16 > row) s1 = -1e30f;
                if (kvl + 32 > row) s2 = -1e30f;
                if (kvl + 48 > row) s3 = -1e30f;
                float mx = fmaxf(fmaxf(s0, s1), fmaxf(s2, s3));
                mx = fmaxf(mx, __shfl_xor(mx, 1));
                mx = fmaxf(mx, __shfl_xor(mx, 2));
                mx = fmaxf(mx, __shfl_xor(mx, 4));
                mx = fmaxf(mx, __shfl_xor(mx, 8));
                float mnew = fmaxf(m_r[i], mx);
                float fac = __expf(m_r[i] - mnew);
                float p0 = __expf(s0 - mnew);
                float p1 = __expf(s1 - mnew);
                float p2 = __expf(s2 - mnew);
                float p3 = __expf(s3 - mnew);
                lv[i] = lv[i] * fac + ((p0 + p1) + (p2 + p3));
                m_r[i] = mnew;
                #pragma unroll
                for (int c8 = 0; c8 < 8; c8++) o[c8][i] *= fac;
                const int pr = g * 4 + i;
                char* pw = psb + w * 2048 + pr * 128;
                const int px = (pr & 7) << 4;
                const int cb2 = l16 << 1;
                *(unsigned short*)(pw + ((cb2)      ^ px)) = f2bf(p0);
                *(unsigned short*)(pw + ((cb2 + 32) ^ px)) = f2bf(p1);
                *(unsigned short*)(pw + ((cb2 + 64) ^ px)) = f2bf(p2);
                *(unsigned short*)(pw + ((cb2 + 96) ^ px)) = f2bf(p3);
            }
            asm volatile("s_waitcnt lgkmcnt(0)" ::: "memory");
            __builtin_amdgcn_sched_barrier(0);

            // ---- PV: 16 MFMAs ----
            bf16x8 pf[2];
            #pragma unroll
            for (int kc = 0; kc < 2; kc++)
                pf[kc] = *(const bf16x8*)(psb + w * 2048 + l16 * 128 + ((kc * 64 + g * 16) ^ rdx));
            __builtin_amdgcn_s_setprio(1);
            #pragma unroll
            for (int c8 = 0; c8 < 8; c8++) {
                const int vrb = (c8 * 16 + l16) * 128 + g * 16;
                #pragma unroll
                for (int kc = 0; kc < 2; kc++) {
                    bf16x8 vf = *(const bf16x8*)(vsb + ((vrb + kc * 64) ^ rdx));
                    o[c8] = __builtin_amdgcn_mfma_f32_16x16x32_bf16(pf[kc], vf, o[c8], 0, 0, 0);
                }
            }
            __builtin_amdgcn_s_setprio(0);
        }

        #pragma unroll
        for (int i = 0; i < 4; i++) {
            float ls = lv[i];
            ls += __shfl_xor(ls, 1);
            ls += __shfl_xor(ls, 2);
            ls += __shfl_xor(ls, 4);
            ls += __shfl_xor(ls, 8);
            float inv = 1.0f / ls;
            int qrow = qb + w * 16 + g * 4 + i;
            size_t rb = ((size_t)(b * NL + qrow)) * ND + h * NDK;
            #pragma unroll
            for (int c8 = 0; c8 < 8; c8++)
                attn_out[rb + c8 * 16 + l16] = f2bf(o[c8][i] * inv);
        }
    }
}

__global__ void ws_signature_kernel(float* y) { if (threadIdx.x == 0) y[0] = 12345.0f; }

extern "C" void kernel_launch(void* const* d_in, const int* in_sizes, int n_in,
                              void* d_out, int out_size, void* d_ws, size_t ws_size,
                              hipStream_t stream)
{
    const float* x     = (const float*)d_in[0];
    const float* w_qkv = (const float*)d_in[1];
    const float* w_o   = (const float*)d_in[2];
    const float* ct    = (const float*)d_in[3];
    const float* st    = (const float*)d_in[4];

    const size_t NTOK = (size_t)NB * NL * ND;
    float* y_out = (float*)d_out;
    float* k_out = y_out + NTOK;
    float* v_out = y_out + 2 * NTOK;

    const size_t need = (6 * NTOK + 4 * (size_t)ND * ND) * sizeof(unsigned short);
    if (ws_size < need) {
        ws_signature_kernel<<<1, 64, 0, stream>>>(y_out);
        return;
    }
    unsigned short* x_bf  = (unsigned short*)d_ws;
    unsigned short* Wt    = x_bf + NTOK;
    unsigned short* Wt_o  = Wt + (size_t)3 * ND * ND;
    unsigned short* q_raw = Wt_o + (size_t)ND * ND;
    unsigned short* q_bf  = q_raw + NTOK;        // unused (kept for layout)
    unsigned short* k_bf  = q_bf + NTOK;
    unsigned short* Vt    = k_bf + NTOK;
    unsigned short* a_bf  = Vt + NTOK;

    convert_bf16_kernel<<<4096, 256, 0, stream>>>(x, x_bf);
    transpose_convert_kernel<<<dim3(96, 32), 256, 0, stream>>>(w_qkv, Wt, ND, 3 * ND);
    transpose_convert_kernel<<<dim3(32, 32), 256, 0, stream>>>(w_o, Wt_o, ND, ND);
    gemm256<0><<<768, 512, 0, stream>>>(x_bf, Wt, nullptr, q_raw, k_out, v_out, ND, 24);
    rope_k_kernel<<<16384, 256, 0, stream>>>(k_out, k_bf, ct, st);
    transpose_v_kernel<<<dim3(2, 32, 32), 256, 0, stream>>>(v_out, Vt);
    attn_kernel<<<dim3(32, 16), 256, 0, stream>>>(q_raw, k_bf, Vt, a_bf, ct, st);
    gemm256<1><<<256, 512, 0, stream>>>(a_bf, Wt_o, y_out, nullptr, nullptr, nullptr, ND, 8);
}